// Round 15
// baseline (1005.407 us; speedup 1.0000x reference)
//
#include <hip/hip_runtime.h>
#include <hip/hip_bf16.h>

// ---------- types ----------
typedef __bf16 bf16x8 __attribute__((ext_vector_type(8)));
typedef float  f32x4  __attribute__((ext_vector_type(4)));
typedef unsigned int u32x4 __attribute__((ext_vector_type(4)));
typedef __attribute__((address_space(3))) unsigned int lds_u32;
typedef const __attribute__((address_space(1))) unsigned int glb_u32;

__device__ inline unsigned short f2bf(float f) {
    union { __hip_bfloat16 h; unsigned short u; } cv;
    cv.h = __float2bfloat16(f);
    return cv.u;
}
__device__ inline float bf2f(unsigned short u) {
    union { unsigned int i; float f; } c; c.i = ((unsigned int)u) << 16; return c.f;
}

// load 8 bf16 (plain layout): 8B at +0 and 8B at +32B
__device__ inline bf16x8 load8(const unsigned short* p) {
    uint2 lo = *(const uint2*)(p);
    uint2 hi = *(const uint2*)(p + 16);
    u32x4 v; v[0] = lo.x; v[1] = lo.y; v[2] = hi.x; v[3] = hi.y;
    return __builtin_bit_cast(bf16x8, v);
}

// swizzled load8 from linear 64B-row LDS: chunk(16B) index XORed with row&3
__device__ inline bf16x8 load8s(const unsigned short* rowbase, int lg, int r3) {
    int b0 = ((((lg >> 1)    ) ^ r3) << 4) + ((lg & 1) << 3);
    int b1 = ((((lg >> 1) + 2) ^ r3) << 4) + ((lg & 1) << 3);
    uint2 lo = *(const uint2*)((const char*)rowbase + b0);
    uint2 hi = *(const uint2*)((const char*)rowbase + b1);
    u32x4 v; v[0] = lo.x; v[1] = lo.y; v[2] = hi.x; v[3] = hi.y;
    return __builtin_bit_cast(bf16x8, v);
}

__device__ inline f32x4 mfma16(bf16x8 a, bf16x8 b, f32x4 c) {
    return __builtin_amdgcn_mfma_f32_16x16x32_bf16(a, b, c, 0, 0, 0);
}

// window-row (global, 0..148959) -> spatial token (0..131071); false if pad
__device__ inline bool winmapT(int gg, int& T) {
    int win = gg / 98, n = gg % 98;
    int wdi = win / 190, rem = win % 190, whi = rem / 19, wwi = rem % 19;
    int td = n / 49, th = (n / 7) % 7, tw = n % 7;
    int sd = (wdi * 2 + td + 1) & 15;
    int sh = whi * 7 + th + 3; if (sh >= 70) sh -= 70;
    int sw = wwi * 7 + tw + 3; if (sw >= 133) sw -= 133;
    if (sh < 64 && sw < 128) { T = (sd * 64 + sh) * 128 + sw; return true; }
    return false;
}

// bijective XCD swizzle (m204)
__device__ inline int xcd_swz(int orig, int nwg) {
    int q = nwg >> 3, r = nwg & 7;
    int xcd = orig & 7, idx = orig >> 3;
    return (xcd < r ? xcd * (q + 1) : r * (q + 1) + (xcd - r) * q) + idx;
}

// ---------- K0: mod = silu(t) @ wa1 @ wa2 + ba2  (1152 floats) ----------
__global__ __launch_bounds__(256) void mod_k(const float* __restrict__ t,
    const float* __restrict__ wa1, const float* __restrict__ wa2,
    const float* __restrict__ ba2, float* __restrict__ mod)
{
    __shared__ float st[192];
    __shared__ float a[24];
    int tid = threadIdx.x;
    if (tid < 192) { float x = t[tid]; st[tid] = x / (1.f + __expf(-x)); }
    __syncthreads();
    if (tid < 24) {
        float s = 0.f;
        for (int c = 0; c < 192; ++c) s += st[c] * wa1[c * 24 + tid];
        a[tid] = s;
    }
    __syncthreads();
    for (int j = tid; j < 1152; j += 256) {
        float s = ba2[j];
        for (int r = 0; r < 24; ++r) s += a[r] * wa2[r * 1152 + j];
        mod[j] = s;
    }
}

// ---------- K1: weight prep ----------
// wqkvH[h][c96][k]: per-head weight rows, c96 = [q 0..31 | k 32..63 | v 64..95]
// bqkvH[h*96+c96]  : matching bias
// btabF (bf16): [mt 8][h 6][fq 7][l16 16][lg 4][fkey 8][e 4] fused bias+mask, -1e30 pads
__global__ __launch_bounds__(256) void prep_k(
    const float* __restrict__ wqkv, const float* __restrict__ bqkv,
    const float* __restrict__ wproj,
    const float* __restrict__ w1, const float* __restrict__ w2,
    const float* __restrict__ relb,
    unsigned short* __restrict__ wqkvH, float* __restrict__ bqkvH,
    unsigned short* __restrict__ wprojT,
    unsigned short* __restrict__ w1T, unsigned short* __restrict__ w2T,
    unsigned short* __restrict__ btabF)
{
    int i = blockIdx.x * 256 + threadIdx.x;
    if (i < 110592) {
        int h = i / 18432, r = i % 18432, c96 = r / 192, k = r % 192;
        int which = c96 >> 5, c = c96 & 31;
        wqkvH[i] = f2bf(wqkv[k * 576 + which * 192 + h * 32 + c]);
        return;
    }
    i -= 110592;
    if (i < 36864)  { int n = i / 192, k = i % 192; wprojT[i] = f2bf(wproj[k * 192 + n]); return; }
    i -= 36864;
    if (i < 147456) { int n = i / 192, k = i % 192; w1T[i] = f2bf(w1[k * 768 + n]); return; }
    i -= 147456;
    if (i < 147456) { int n = i / 768, k = i % 768; w2T[i] = f2bf(w2[k * 192 + n]); return; }
    i -= 147456;
    if (i < 688128) {
        int mt = i / 86016, r1 = i % 86016;
        int h  = r1 / 14336, r2 = r1 % 14336;
        int fq = r2 / 2048,  r3 = r2 % 2048;
        int l16 = r3 / 128,  r4 = r3 % 128;
        int lg  = r4 / 32,   r5 = r4 % 32;
        int fkey = r5 / 4,   e  = r5 % 4;
        int q = fq * 16 + l16, key = fkey * 16 + lg * 4 + e;
        float val;
        if (fkey == 7 || q >= 98 || key >= 98) {
            val = -1e30f;
        } else {
            int tdn = q / 49, thn = (q / 7) % 7, twn = q % 7;
            int tdm = key / 49, thm = (key / 7) % 7, twm = key % 7;
            int idx = (tdn - tdm + 1) * 169 + (thn - thm + 6) * 13 + (twn - twm + 6);
            float b = relb[idx * 6 + h];
            int bd = mt & 1, bh = (mt >> 1) & 1, bw = (mt >> 2) & 1;
            int idn = (bd ? (tdn == 0 ? 1 : 2) : 0) * 9 + (bh ? (thn < 4 ? 1 : 2) : 0) * 3 + (bw ? (twn < 4 ? 1 : 2) : 0);
            int idm = (bd ? (tdm == 0 ? 1 : 2) : 0) * 9 + (bh ? (thm < 4 ? 1 : 2) : 0) * 3 + (bw ? (twm < 4 ? 1 : 2) : 0);
            val = b + ((idn != idm) ? -100.f : 0.f);
        }
        btabF[i] = f2bf(val);
        return;
    }
    i -= 688128;
    if (i < 576) {
        int h = i / 96, c96 = i % 96;
        int which = c96 >> 5, c = c96 & 31;
        bqkvH[i] = bqkv[which * 192 + h * 32 + c];
    }
}

// ---------- lnwin: x -> LN+modulate(MSA) + window gather -> ywin bf16 [148960][192] ----------
__global__ __launch_bounds__(256) void lnwin_k(const float* __restrict__ x,
    const float* __restrict__ mod, unsigned short* __restrict__ ywin)
{
    int tok = blockIdx.x * 4 + (threadIdx.x >> 6);
    int lane = threadIdx.x & 63;
    int T;
    size_t ob = (size_t)tok * 192;
    if (winmapT(tok, T)) {
        const float* p = x + (size_t)T * 192;
        float x0 = p[lane], xa = p[64 + lane], xb = p[128 + lane];
        float s = x0 + xa + xb, q = x0 * x0 + xa * xa + xb * xb;
        for (int m = 32; m; m >>= 1) { s += __shfl_xor(s, m); q += __shfl_xor(q, m); }
        float mean = s * (1.f / 192.f);
        float var  = q * (1.f / 192.f) - mean * mean;
        float rstd = rsqrtf(var + 1e-6f);
        ywin[ob + lane]       = f2bf((x0 - mean) * rstd * (1.f + mod[192 + lane])       + mod[lane]);
        ywin[ob + 64 + lane]  = f2bf((xa - mean) * rstd * (1.f + mod[192 + 64 + lane])  + mod[64 + lane]);
        ywin[ob + 128 + lane] = f2bf((xb - mean) * rstd * (1.f + mod[192 + 128 + lane]) + mod[128 + lane]);
    } else {
        ywin[ob + lane] = 0; ywin[ob + 64 + lane] = 0; ywin[ob + 128 + lane] = 0;
    }
}

// ---------- ln2: x1(fp32) -> LN+modulate(MLP) -> y2 bf16 [131072][192] ----------
__global__ __launch_bounds__(256) void ln2_k(const float* __restrict__ x1,
    const float* __restrict__ mod, unsigned short* __restrict__ y2)
{
    int tok = blockIdx.x * 4 + (threadIdx.x >> 6);
    int lane = threadIdx.x & 63;
    const float* p = x1 + (size_t)tok * 192;
    float x0 = p[lane], xa = p[64 + lane], xb = p[128 + lane];
    float s = x0 + xa + xb, q = x0 * x0 + xa * xa + xb * xb;
    for (int m = 32; m; m >>= 1) { s += __shfl_xor(s, m); q += __shfl_xor(q, m); }
    float mean = s * (1.f / 192.f);
    float var  = q * (1.f / 192.f) - mean * mean;
    float rstd = rsqrtf(var + 1e-6f);
    size_t ob = (size_t)tok * 192;
    y2[ob + lane]       = f2bf((x0 - mean) * rstd * (1.f + mod[768 + lane])       + mod[576 + lane]);
    y2[ob + 64 + lane]  = f2bf((xa - mean) * rstd * (1.f + mod[768 + 64 + lane])  + mod[576 + 64 + lane]);
    y2[ob + 128 + lane] = f2bf((xb - mean) * rstd * (1.f + mod[768 + 128 + lane]) + mod[576 + 128 + lane]);
}

// ---------- GEMM: DOUBLE-BUFFERED 2-phase (unchanged from r14) ----------
template<int FN, int EPI>
__global__ __launch_bounds__(256) void gemm_k(
    const unsigned short* __restrict__ A, const unsigned short* __restrict__ BT,
    const float* __restrict__ bias, unsigned short* __restrict__ outB, float* outF,
    const float* __restrict__ auxF, const float* __restrict__ mod,
    int M, int N, int K, int nx)
{
    constexpr int BN = FN * 32;
    __shared__ unsigned short As[2][128 * 32];
    __shared__ unsigned short Bs[2][BN * 32];
    const int t = threadIdx.x;
    const int wg = xcd_swz(blockIdx.x, gridDim.x);
    const int n0 = (wg % nx) * BN, m0 = (wg / nx) * 128;
    const int wid = t >> 6, lane = t & 63;
    const int lg = lane >> 4, l16 = lane & 15;
    const int wm = (wid >> 1) * 64, wn = (wid & 1) * (FN * 16);
    f32x4 acc[4][FN] = {};

    int arow[2], acs[2];
    #pragma unroll
    for (int j = 0; j < 2; ++j) {
        int p = t + j * 256;
        arow[j] = p >> 2;
        acs[j] = (p & 3) ^ (arow[j] & 3);
    }
    const unsigned short* asrc[2];
    const unsigned short* bsrc[BN / 64];
    #pragma unroll
    for (int j = 0; j < 2; ++j) {
        int gr = m0 + arow[j];
        asrc[j] = A + (size_t)(gr < M ? gr : 0) * K + acs[j] * 8;
    }
    #pragma unroll
    for (int j = 0; j < BN / 64; ++j) {
        int gn = n0 + arow[j];
        bsrc[j] = BT + (size_t)(gn < N ? gn : 0) * K + acs[j] * 8;
    }

    const int NS = K >> 5;

    #pragma unroll
    for (int j = 0; j < 2; ++j)
        __builtin_amdgcn_global_load_lds((glb_u32*)(asrc[j]),
            (lds_u32*)((char*)&As[0][0] + wid * 1024 + j * 4096), 16, 0, 0);
    #pragma unroll
    for (int j = 0; j < BN / 64; ++j)
        __builtin_amdgcn_global_load_lds((glb_u32*)(bsrc[j]),
            (lds_u32*)((char*)&Bs[0][0] + wid * 1024 + j * 4096), 16, 0, 0);
    __syncthreads();

    for (int s = 0; s < NS; ++s) {
        const int cur = s & 1;
        if (s + 1 < NS) {
            const int kk = (s + 1) << 5;
            #pragma unroll
            for (int j = 0; j < 2; ++j)
                __builtin_amdgcn_global_load_lds((glb_u32*)(asrc[j] + kk),
                    (lds_u32*)((char*)&As[cur ^ 1][0] + wid * 1024 + j * 4096), 16, 0, 0);
            #pragma unroll
            for (int j = 0; j < BN / 64; ++j)
                __builtin_amdgcn_global_load_lds((glb_u32*)(bsrc[j] + kk),
                    (lds_u32*)((char*)&Bs[cur ^ 1][0] + wid * 1024 + j * 4096), 16, 0, 0);
        }
        bf16x8 af[4], bv[FN];
        #pragma unroll
        for (int i = 0; i < 4; ++i) {
            int r = wm + i * 16 + l16;
            af[i] = load8s(&As[cur][r * 32], lg, r & 3);
        }
        #pragma unroll
        for (int j = 0; j < FN; ++j) {
            int r = wn + j * 16 + l16;
            bv[j] = load8s(&Bs[cur][r * 32], lg, r & 3);
        }
        #pragma unroll
        for (int i = 0; i < 4; ++i)
        #pragma unroll
        for (int j = 0; j < FN; ++j)
            acc[i][j] = mfma16(af[i], bv[j], acc[i][j]);
        __syncthreads();
    }

    #pragma unroll
    for (int i = 0; i < 4; ++i)
    #pragma unroll
    for (int j = 0; j < FN; ++j) {
        int gcol = n0 + wn + j * 16 + l16;
        if (gcol >= N) continue;
        float b = bias[gcol];
        #pragma unroll
        for (int e = 0; e < 4; ++e) {
            int grow = m0 + wm + i * 16 + lg * 4 + e;
            if (grow >= M) continue;
            float v = acc[i][j][e] + b;
            if (EPI == 1) {
                float gl = 0.5f * v * (1.f + erff(v * 0.70710678118654752f));
                outB[(size_t)grow * N + gcol] = f2bf(gl);
            } else if (EPI == 2) {
                int T;
                if (winmapT(grow, T)) {
                    size_t idx = (size_t)T * 192 + gcol;
                    outF[idx] = auxF[idx] + mod[384 + gcol] * v;
                }
            } else {
                size_t idx = (size_t)grow * 192 + gcol;
                outF[idx] = outF[idx] + mod[960 + gcol] * v;
            }
        }
    }
}

// ---------- FUSED qkv-GEMM + attention: one block per window ----------
// A = ywin window rows [128][192] in LDS (rows>=98 zero), staged once.
// Per head: B = wqkvH[h][96][192] staged from L2; 72-MFMA straight-line GEMM;
// C+bias written directly to Qs/Ks/VT LDS; swapped-QK attention; out -> attn_c.
// Pad rows (>=98) become bias constants: keys masked by -1e30 table, pad-key P==0.
__global__ __launch_bounds__(256) void qkvattn_k(
    const unsigned short* __restrict__ ywin, const unsigned short* __restrict__ wqkvH,
    const float* __restrict__ bqkvH, const unsigned short* __restrict__ btabF,
    unsigned short* __restrict__ out)
{
    __shared__ unsigned short As[128 * 196];   // stride 196 (392B) -> conflict-free frags
    __shared__ unsigned short Bs[96 * 196];
    __shared__ unsigned short Qs[112 * 46];
    __shared__ unsigned short Ks[112 * 46];
    __shared__ unsigned short VT[32 * 142];

    const int win = xcd_swz(blockIdx.x, 1520);
    const int t = threadIdx.x;
    const int wid = t >> 6, lane = t & 63;
    const int lg = lane >> 4, l16 = lane & 15;
    const int wr = wid >> 1, wc = wid & 1;
    const size_t rb = (size_t)win * 98;

    const int wdi = win / 190, remw = win % 190, whi = remw / 19, wwi = remw % 19;
    const int mt = (wdi == 7 ? 1 : 0) | (whi == 9 ? 2 : 0) | (wwi == 18 ? 4 : 0);
    const float SCALE = 0.17677669529663687f;

    // stage A once: [128][192] (rows 98..127 zero)
    for (int p = t; p < 128 * 24; p += 256) {
        int row = p / 24, ch = p % 24;
        uint4 w = make_uint4(0u, 0u, 0u, 0u);
        if (row < 98) w = *(const uint4*)(ywin + (rb + row) * 192 + ch * 8);
        *(uint2*)(&As[row * 196 + ch * 8])     = make_uint2(w.x, w.y);
        *(uint2*)(&As[row * 196 + ch * 8 + 4]) = make_uint2(w.z, w.w);
    }

    for (int h = 0; h < 6; ++h) {
        // stage B = wqkvH[h]: [96][192]
        const unsigned short* Wh = wqkvH + (size_t)h * 96 * 192;
        for (int p = t; p < 96 * 24; p += 256) {
            int row = p / 24, ch = p % 24;
            uint4 w = *(const uint4*)(Wh + row * 192 + ch * 8);
            *(uint2*)(&Bs[row * 196 + ch * 8])     = make_uint2(w.x, w.y);
            *(uint2*)(&Bs[row * 196 + ch * 8 + 4]) = make_uint2(w.z, w.w);
        }
        __syncthreads();   // A+B staged; also prev-head attn-read -> this-head C-write edge

        // GEMM: C[128][96] = A @ B^T, straight-line over K=192
        __builtin_amdgcn_s_setprio(1);
        f32x4 acc[4][3] = {};
        #pragma unroll
        for (int kb = 0; kb < 6; ++kb) {
            bf16x8 af[4], bv[3];
            #pragma unroll
            for (int i2 = 0; i2 < 4; ++i2)
                af[i2] = load8(&As[(wr * 64 + i2 * 16 + l16) * 196 + kb * 32 + 4 * lg]);
            #pragma unroll
            for (int j = 0; j < 3; ++j)
                bv[j] = load8(&Bs[(wc * 48 + j * 16 + l16) * 196 + kb * 32 + 4 * lg]);
            #pragma unroll
            for (int i2 = 0; i2 < 4; ++i2)
            #pragma unroll
            for (int j = 0; j < 3; ++j)
                acc[i2][j] = mfma16(af[i2], bv[j], acc[i2][j]);
        }
        __builtin_amdgcn_s_setprio(0);

        // C + bias -> Qs/Ks/VT (LDS-only scatter)
        #pragma unroll
        for (int j = 0; j < 3; ++j) {
            int c96 = wc * 48 + j * 16 + l16;
            float bb = bqkvH[h * 96 + c96];
            int which = c96 >> 5, c = c96 & 31;
            #pragma unroll
            for (int i2 = 0; i2 < 4; ++i2)
            #pragma unroll
            for (int e = 0; e < 4; ++e) {
                int row = wr * 64 + i2 * 16 + lg * 4 + e;
                unsigned short val = f2bf(acc[i2][j][e] + bb);
                if (which == 0)      { if (row < 112) Qs[row * 46 + c] = val; }
                else if (which == 1) { if (row < 112) Ks[row * 46 + c] = val; }
                else                 { VT[c * 142 + row] = val; }  // rows 112..127 finite, x0 in PV
            }
        }
        __syncthreads();   // C visible to all waves

        // attention for head h (swapped-QK, in-register P)
        const unsigned short* btW = btabF + (size_t)(mt * 6 + h) * 14336;
        #pragma unroll
        for (int fi = 0; fi < 2; ++fi) {
            const int fq = wid + fi * 4;
            if (fq >= 7) break;   // wave-uniform

            const uint4* bp = (const uint4*)(btW + fq * 2048 + l16 * 128 + lg * 32);
            uint4 b0 = bp[0], b1 = bp[1], b2 = bp[2], b3 = bp[3];
            const unsigned bt32[16] = {b0.x, b0.y, b0.z, b0.w, b1.x, b1.y, b1.z, b1.w,
                                       b2.x, b2.y, b2.z, b2.w, b3.x, b3.y, b3.z, b3.w};

            bf16x8 qa = load8(Qs + (fq * 16 + l16) * 46 + 4 * lg);
            f32x4 sc[7];
            #pragma unroll
            for (int fk = 0; fk < 7; ++fk) {
                bf16x8 kb = load8(Ks + (fk * 16 + l16) * 46 + 4 * lg);
                f32x4 z = {};
                sc[fk] = mfma16(kb, qa, z);
            }

            float mx = -1e30f;
            #pragma unroll
            for (int fk = 0; fk < 7; ++fk)
            #pragma unroll
            for (int e = 0; e < 4; ++e) {
                unsigned short bu = (unsigned short)(bt32[fk * 2 + (e >> 1)] >> ((e & 1) * 16));
                float s = fmaf(sc[fk][e], SCALE, bf2f(bu));
                sc[fk][e] = s;
                mx = fmaxf(mx, s);
            }
            mx = fmaxf(mx, __shfl_xor(mx, 16));
            mx = fmaxf(mx, __shfl_xor(mx, 32));
            float sum = 0.f;
            #pragma unroll
            for (int fk = 0; fk < 7; ++fk)
            #pragma unroll
            for (int e = 0; e < 4; ++e) {
                float p = __expf(sc[fk][e] - mx);
                sc[fk][e] = p;
                sum += p;
            }
            sum += __shfl_xor(sum, 16);
            sum += __shfl_xor(sum, 32);
            float rinv = 1.f / sum;

            bf16x8 sa[4];
            #pragma unroll
            for (int ks = 0; ks < 4; ++ks) {
                u32x4 w;
                w[0] = (unsigned)f2bf(sc[2 * ks][0]) | ((unsigned)f2bf(sc[2 * ks][1]) << 16);
                w[1] = (unsigned)f2bf(sc[2 * ks][2]) | ((unsigned)f2bf(sc[2 * ks][3]) << 16);
                if (ks < 3) {
                    w[2] = (unsigned)f2bf(sc[2 * ks + 1][0]) | ((unsigned)f2bf(sc[2 * ks + 1][1]) << 16);
                    w[3] = (unsigned)f2bf(sc[2 * ks + 1][2]) | ((unsigned)f2bf(sc[2 * ks + 1][3]) << 16);
                } else {
                    w[2] = 0u; w[3] = 0u;   // keys 112..127 exact zero
                }
                sa[ks] = __builtin_bit_cast(bf16x8, w);
            }
            float rv[4];
            #pragma unroll
            for (int e = 0; e < 4; ++e) rv[e] = __shfl(rinv, lg * 4 + e);

            #pragma unroll
            for (int fn = 0; fn < 2; ++fn) {
                f32x4 o = {};
                #pragma unroll
                for (int ks = 0; ks < 4; ++ks) {
                    bf16x8 vb = load8(VT + (fn * 16 + l16) * 142 + ks * 32 + 4 * lg);
                    o = mfma16(sa[ks], vb, o);
                }
                #pragma unroll
                for (int e = 0; e < 4; ++e) {
                    int r = fq * 16 + lg * 4 + e;
                    if (r < 98) {
                        out[(rb + r) * 192 + h * 32 + fn * 16 + l16] = f2bf(o[e] * rv[e]);
                    }
                }
            }
        }
        // no barrier here: next head's stage+barrier provides the edge
    }
}

// ---------- launch ----------
// ws_size = 384 MiB. d_out (fp32 [131072][192]) is ALSO the x1 buffer.
extern "C" void kernel_launch(void* const* d_in, const int* in_sizes, int n_in,
                              void* d_out, int out_size, void* d_ws, size_t ws_size,
                              hipStream_t stream)
{
    const float* x      = (const float*)d_in[0];
    const float* tvec   = (const float*)d_in[2];
    const float* w_qkv  = (const float*)d_in[3];
    const float* b_qkv  = (const float*)d_in[4];
    const float* relb   = (const float*)d_in[5];
    const float* w_proj = (const float*)d_in[6];
    const float* b_proj = (const float*)d_in[7];
    const float* w1     = (const float*)d_in[8];
    const float* b1     = (const float*)d_in[9];
    const float* w2     = (const float*)d_in[10];
    const float* b2     = (const float*)d_in[11];
    const float* wa1    = (const float*)d_in[12];
    const float* wa2    = (const float*)d_in[13];
    const float* ba2    = (const float*)d_in[14];

    char* ws = (char*)d_ws;
    float*          mod    = (float*)ws;                        // 4,608
    float*          bqkvH  = (float*)(ws + 4608);               // 2,304
    unsigned short* wqkvH  = (unsigned short*)(ws + 2101760);   // 221,184
    unsigned short* wprojT = (unsigned short*)(ws + 2322944);   // 73,728
    unsigned short* w1T    = (unsigned short*)(ws + 2396672);   // 294,912
    unsigned short* w2T    = (unsigned short*)(ws + 2691584);   // 294,912
    unsigned short* btabF  = (unsigned short*)(ws + 2986496);   // 1,376,256
    unsigned short* h      = (unsigned short*)(ws + 4834304);   // [131072][768] bf16
    unsigned short* attn_c = (unsigned short*)(ws + 176436224); // [148960][192] bf16
    unsigned short* ywin   = (unsigned short*)(ws + 233636864); // [148960][192] bf16
    unsigned short* y2b    = (unsigned short*)(ws + 290837504); // [131072][192] bf16
    float*          dout   = (float*)d_out;                     // fp32 out == x1 buffer

    mod_k<<<1, 256, 0, stream>>>(tvec, wa1, wa2, ba2, mod);
    prep_k<<<4418, 256, 0, stream>>>(w_qkv, b_qkv, w_proj, w1, w2, relb,
                                     wqkvH, bqkvH, wprojT, w1T, w2T, btabF);
    lnwin_k<<<37240, 256, 0, stream>>>(x, mod, ywin);

    // fused qkv-GEMM + attention
    qkvattn_k<<<1520, 256, 0, stream>>>(ywin, wqkvH, bqkvH, btabF, attn_c);
    // proj + residual scatter -> fp32 x1 (in d_out)
    gemm_k<2, 2><<<3 * 1164, 256, 0, stream>>>(
        attn_c, wprojT, b_proj, nullptr, dout, x, mod, 148960, 192, 192, 3);

    ln2_k<<<32768, 256, 0, stream>>>(dout, mod, y2b);

    gemm_k<4, 1><<<6 * 1024, 256, 0, stream>>>(
        y2b, w1T, b1, h, nullptr, nullptr, mod, 131072, 768, 192, 6);
    gemm_k<2, 3><<<3 * 1024, 256, 0, stream>>>(
        h, w2T, b2, nullptr, dout, nullptr, mod, 131072, 192, 768, 3);
}

// Round 16
// 905.523 us; speedup vs baseline: 1.1103x; 1.1103x over previous
//
#include <hip/hip_runtime.h>
#include <hip/hip_bf16.h>

// ---------- types ----------
typedef __bf16 bf16x8 __attribute__((ext_vector_type(8)));
typedef float  f32x4  __attribute__((ext_vector_type(4)));
typedef unsigned int u32x4 __attribute__((ext_vector_type(4)));
typedef __attribute__((address_space(3))) unsigned int lds_u32;
typedef const __attribute__((address_space(1))) unsigned int glb_u32;

__device__ inline unsigned short f2bf(float f) {
    union { __hip_bfloat16 h; unsigned short u; } cv;
    cv.h = __float2bfloat16(f);
    return cv.u;
}
__device__ inline float bf2f(unsigned short u) {
    union { unsigned int i; float f; } c; c.i = ((unsigned int)u) << 16; return c.f;
}

// load 8 bf16 (plain layout): 8B at +0 and 8B at +32B
__device__ inline bf16x8 load8(const unsigned short* p) {
    uint2 lo = *(const uint2*)(p);
    uint2 hi = *(const uint2*)(p + 16);
    u32x4 v; v[0] = lo.x; v[1] = lo.y; v[2] = hi.x; v[3] = hi.y;
    return __builtin_bit_cast(bf16x8, v);
}

// swizzled load8 from linear 64B-row LDS: chunk(16B) index XORed with row&3
__device__ inline bf16x8 load8s(const unsigned short* rowbase, int lg, int r3) {
    int b0 = ((((lg >> 1)    ) ^ r3) << 4) + ((lg & 1) << 3);
    int b1 = ((((lg >> 1) + 2) ^ r3) << 4) + ((lg & 1) << 3);
    uint2 lo = *(const uint2*)((const char*)rowbase + b0);
    uint2 hi = *(const uint2*)((const char*)rowbase + b1);
    u32x4 v; v[0] = lo.x; v[1] = lo.y; v[2] = hi.x; v[3] = hi.y;
    return __builtin_bit_cast(bf16x8, v);
}

__device__ inline f32x4 mfma16(bf16x8 a, bf16x8 b, f32x4 c) {
    return __builtin_amdgcn_mfma_f32_16x16x32_bf16(a, b, c, 0, 0, 0);
}

// window-row (global, 0..148959) -> spatial token (0..131071); false if pad
__device__ inline bool winmapT(int gg, int& T) {
    int win = gg / 98, n = gg % 98;
    int wdi = win / 190, rem = win % 190, whi = rem / 19, wwi = rem % 19;
    int td = n / 49, th = (n / 7) % 7, tw = n % 7;
    int sd = (wdi * 2 + td + 1) & 15;
    int sh = whi * 7 + th + 3; if (sh >= 70) sh -= 70;
    int sw = wwi * 7 + tw + 3; if (sw >= 133) sw -= 133;
    if (sh < 64 && sw < 128) { T = (sd * 64 + sh) * 128 + sw; return true; }
    return false;
}

// bijective XCD swizzle (m204)
__device__ inline int xcd_swz(int orig, int nwg) {
    int q = nwg >> 3, r = nwg & 7;
    int xcd = orig & 7, idx = orig >> 3;
    return (xcd < r ? xcd * (q + 1) : r * (q + 1) + (xcd - r) * q) + idx;
}

// ---------- K0: mod = silu(t) @ wa1 @ wa2 + ba2  (1152 floats) ----------
__global__ __launch_bounds__(256) void mod_k(const float* __restrict__ t,
    const float* __restrict__ wa1, const float* __restrict__ wa2,
    const float* __restrict__ ba2, float* __restrict__ mod)
{
    __shared__ float st[192];
    __shared__ float a[24];
    int tid = threadIdx.x;
    if (tid < 192) { float x = t[tid]; st[tid] = x / (1.f + __expf(-x)); }
    __syncthreads();
    if (tid < 24) {
        float s = 0.f;
        for (int c = 0; c < 192; ++c) s += st[c] * wa1[c * 24 + tid];
        a[tid] = s;
    }
    __syncthreads();
    for (int j = tid; j < 1152; j += 256) {
        float s = ba2[j];
        for (int r = 0; r < 24; ++r) s += a[r] * wa2[r * 1152 + j];
        mod[j] = s;
    }
}

// ---------- K1: weight prep ----------
// wqkvH[h][c96][k]: per-head weight rows, c96 = [q 0..31 | k 32..63 | v 64..95]
// bqkvH[h*96+c96]; btabF fused bias+mask table (swapped-QK fragment order)
__global__ __launch_bounds__(256) void prep_k(
    const float* __restrict__ wqkv, const float* __restrict__ bqkv,
    const float* __restrict__ wproj,
    const float* __restrict__ w1, const float* __restrict__ w2,
    const float* __restrict__ relb,
    unsigned short* __restrict__ wqkvH, float* __restrict__ bqkvH,
    unsigned short* __restrict__ wprojT,
    unsigned short* __restrict__ w1T, unsigned short* __restrict__ w2T,
    unsigned short* __restrict__ btabF)
{
    int i = blockIdx.x * 256 + threadIdx.x;
    if (i < 110592) {
        int h = i / 18432, r = i % 18432, c96 = r / 192, k = r % 192;
        int which = c96 >> 5, c = c96 & 31;
        wqkvH[i] = f2bf(wqkv[k * 576 + which * 192 + h * 32 + c]);
        return;
    }
    i -= 110592;
    if (i < 36864)  { int n = i / 192, k = i % 192; wprojT[i] = f2bf(wproj[k * 192 + n]); return; }
    i -= 36864;
    if (i < 147456) { int n = i / 192, k = i % 192; w1T[i] = f2bf(w1[k * 768 + n]); return; }
    i -= 147456;
    if (i < 147456) { int n = i / 768, k = i % 768; w2T[i] = f2bf(w2[k * 192 + n]); return; }
    i -= 147456;
    if (i < 688128) {
        int mt = i / 86016, r1 = i % 86016;
        int h  = r1 / 14336, r2 = r1 % 14336;
        int fq = r2 / 2048,  r3 = r2 % 2048;
        int l16 = r3 / 128,  r4 = r3 % 128;
        int lg  = r4 / 32,   r5 = r4 % 32;
        int fkey = r5 / 4,   e  = r5 % 4;
        int q = fq * 16 + l16, key = fkey * 16 + lg * 4 + e;
        float val;
        if (fkey == 7 || q >= 98 || key >= 98) {
            val = -1e30f;
        } else {
            int tdn = q / 49, thn = (q / 7) % 7, twn = q % 7;
            int tdm = key / 49, thm = (key / 7) % 7, twm = key % 7;
            int idx = (tdn - tdm + 1) * 169 + (thn - thm + 6) * 13 + (twn - twm + 6);
            float b = relb[idx * 6 + h];
            int bd = mt & 1, bh = (mt >> 1) & 1, bw = (mt >> 2) & 1;
            int idn = (bd ? (tdn == 0 ? 1 : 2) : 0) * 9 + (bh ? (thn < 4 ? 1 : 2) : 0) * 3 + (bw ? (twn < 4 ? 1 : 2) : 0);
            int idm = (bd ? (tdm == 0 ? 1 : 2) : 0) * 9 + (bh ? (thm < 4 ? 1 : 2) : 0) * 3 + (bw ? (twm < 4 ? 1 : 2) : 0);
            val = b + ((idn != idm) ? -100.f : 0.f);
        }
        btabF[i] = f2bf(val);
        return;
    }
    i -= 688128;
    if (i < 576) {
        int h = i / 96, c96 = i % 96;
        int which = c96 >> 5, c = c96 & 31;
        bqkvH[i] = bqkv[which * 192 + h * 32 + c];
    }
}

// ---------- lnwin: x -> LN+modulate(MSA) + window gather -> ywin bf16 [148960][192] ----------
__global__ __launch_bounds__(256) void lnwin_k(const float* __restrict__ x,
    const float* __restrict__ mod, unsigned short* __restrict__ ywin)
{
    int tok = blockIdx.x * 4 + (threadIdx.x >> 6);
    int lane = threadIdx.x & 63;
    int T;
    size_t ob = (size_t)tok * 192;
    if (winmapT(tok, T)) {
        const float* p = x + (size_t)T * 192;
        float x0 = p[lane], xa = p[64 + lane], xb = p[128 + lane];
        float s = x0 + xa + xb, q = x0 * x0 + xa * xa + xb * xb;
        for (int m = 32; m; m >>= 1) { s += __shfl_xor(s, m); q += __shfl_xor(q, m); }
        float mean = s * (1.f / 192.f);
        float var  = q * (1.f / 192.f) - mean * mean;
        float rstd = rsqrtf(var + 1e-6f);
        ywin[ob + lane]       = f2bf((x0 - mean) * rstd * (1.f + mod[192 + lane])       + mod[lane]);
        ywin[ob + 64 + lane]  = f2bf((xa - mean) * rstd * (1.f + mod[192 + 64 + lane])  + mod[64 + lane]);
        ywin[ob + 128 + lane] = f2bf((xb - mean) * rstd * (1.f + mod[192 + 128 + lane]) + mod[128 + lane]);
    } else {
        ywin[ob + lane] = 0; ywin[ob + 64 + lane] = 0; ywin[ob + 128 + lane] = 0;
    }
}

// ---------- ln2: x1(fp32) -> LN+modulate(MLP) -> y2 bf16 [131072][192] ----------
__global__ __launch_bounds__(256) void ln2_k(const float* __restrict__ x1,
    const float* __restrict__ mod, unsigned short* __restrict__ y2)
{
    int tok = blockIdx.x * 4 + (threadIdx.x >> 6);
    int lane = threadIdx.x & 63;
    const float* p = x1 + (size_t)tok * 192;
    float x0 = p[lane], xa = p[64 + lane], xb = p[128 + lane];
    float s = x0 + xa + xb, q = x0 * x0 + xa * xa + xb * xb;
    for (int m = 32; m; m >>= 1) { s += __shfl_xor(s, m); q += __shfl_xor(q, m); }
    float mean = s * (1.f / 192.f);
    float var  = q * (1.f / 192.f) - mean * mean;
    float rstd = rsqrtf(var + 1e-6f);
    size_t ob = (size_t)tok * 192;
    y2[ob + lane]       = f2bf((x0 - mean) * rstd * (1.f + mod[768 + lane])       + mod[576 + lane]);
    y2[ob + 64 + lane]  = f2bf((xa - mean) * rstd * (1.f + mod[768 + 64 + lane])  + mod[576 + 64 + lane]);
    y2[ob + 128 + lane] = f2bf((xb - mean) * rstd * (1.f + mod[768 + 128 + lane]) + mod[576 + 128 + lane]);
}

// ---------- GEMM: DOUBLE-BUFFERED 2-phase (unchanged from r14) ----------
template<int FN, int EPI>
__global__ __launch_bounds__(256) void gemm_k(
    const unsigned short* __restrict__ A, const unsigned short* __restrict__ BT,
    const float* __restrict__ bias, unsigned short* __restrict__ outB, float* outF,
    const float* __restrict__ auxF, const float* __restrict__ mod,
    int M, int N, int K, int nx)
{
    constexpr int BN = FN * 32;
    __shared__ unsigned short As[2][128 * 32];
    __shared__ unsigned short Bs[2][BN * 32];
    const int t = threadIdx.x;
    const int wg = xcd_swz(blockIdx.x, gridDim.x);
    const int n0 = (wg % nx) * BN, m0 = (wg / nx) * 128;
    const int wid = t >> 6, lane = t & 63;
    const int lg = lane >> 4, l16 = lane & 15;
    const int wm = (wid >> 1) * 64, wn = (wid & 1) * (FN * 16);
    f32x4 acc[4][FN] = {};

    int arow[2], acs[2];
    #pragma unroll
    for (int j = 0; j < 2; ++j) {
        int p = t + j * 256;
        arow[j] = p >> 2;
        acs[j] = (p & 3) ^ (arow[j] & 3);
    }
    const unsigned short* asrc[2];
    const unsigned short* bsrc[BN / 64];
    #pragma unroll
    for (int j = 0; j < 2; ++j) {
        int gr = m0 + arow[j];
        asrc[j] = A + (size_t)(gr < M ? gr : 0) * K + acs[j] * 8;
    }
    #pragma unroll
    for (int j = 0; j < BN / 64; ++j) {
        int gn = n0 + arow[j];
        bsrc[j] = BT + (size_t)(gn < N ? gn : 0) * K + acs[j] * 8;
    }

    const int NS = K >> 5;

    #pragma unroll
    for (int j = 0; j < 2; ++j)
        __builtin_amdgcn_global_load_lds((glb_u32*)(asrc[j]),
            (lds_u32*)((char*)&As[0][0] + wid * 1024 + j * 4096), 16, 0, 0);
    #pragma unroll
    for (int j = 0; j < BN / 64; ++j)
        __builtin_amdgcn_global_load_lds((glb_u32*)(bsrc[j]),
            (lds_u32*)((char*)&Bs[0][0] + wid * 1024 + j * 4096), 16, 0, 0);
    __syncthreads();

    for (int s = 0; s < NS; ++s) {
        const int cur = s & 1;
        if (s + 1 < NS) {
            const int kk = (s + 1) << 5;
            #pragma unroll
            for (int j = 0; j < 2; ++j)
                __builtin_amdgcn_global_load_lds((glb_u32*)(asrc[j] + kk),
                    (lds_u32*)((char*)&As[cur ^ 1][0] + wid * 1024 + j * 4096), 16, 0, 0);
            #pragma unroll
            for (int j = 0; j < BN / 64; ++j)
                __builtin_amdgcn_global_load_lds((glb_u32*)(bsrc[j] + kk),
                    (lds_u32*)((char*)&Bs[cur ^ 1][0] + wid * 1024 + j * 4096), 16, 0, 0);
        }
        bf16x8 af[4], bv[FN];
        #pragma unroll
        for (int i = 0; i < 4; ++i) {
            int r = wm + i * 16 + l16;
            af[i] = load8s(&As[cur][r * 32], lg, r & 3);
        }
        #pragma unroll
        for (int j = 0; j < FN; ++j) {
            int r = wn + j * 16 + l16;
            bv[j] = load8s(&Bs[cur][r * 32], lg, r & 3);
        }
        #pragma unroll
        for (int i = 0; i < 4; ++i)
        #pragma unroll
        for (int j = 0; j < FN; ++j)
            acc[i][j] = mfma16(af[i], bv[j], acc[i][j]);
        __syncthreads();
    }

    #pragma unroll
    for (int i = 0; i < 4; ++i)
    #pragma unroll
    for (int j = 0; j < FN; ++j) {
        int gcol = n0 + wn + j * 16 + l16;
        if (gcol >= N) continue;
        float b = bias[gcol];
        #pragma unroll
        for (int e = 0; e < 4; ++e) {
            int grow = m0 + wm + i * 16 + lg * 4 + e;
            if (grow >= M) continue;
            float v = acc[i][j][e] + b;
            if (EPI == 1) {
                float gl = 0.5f * v * (1.f + erff(v * 0.70710678118654752f));
                outB[(size_t)grow * N + gcol] = f2bf(gl);
            } else if (EPI == 2) {
                int T;
                if (winmapT(grow, T)) {
                    size_t idx = (size_t)T * 192 + gcol;
                    outF[idx] = auxF[idx] + mod[384 + gcol] * v;
                }
            } else {
                size_t idx = (size_t)grow * 192 + gcol;
                outF[idx] = outF[idx] + mod[960 + gcol] * v;
            }
        }
    }
}

// ---------- FUSED qkv-GEMM + attention v2: 2 blocks/CU ----------
// A = ywin window rows [112][196-stride] LDS (rows 98..111 zero), staged once.
// B = per-head weights in REGISTERS (18 x bf16x8, L2-resident source, reused 4x).
// C quadrant (wr,wc); wr=1 computes i2<3 only (C rows 112..127 never needed:
// VT cols 112..127 zero-init once, multiplied by exact-zero P). 2 barriers/head.
__global__ __launch_bounds__(256, 2) void qkvattn_k(
    const unsigned short* __restrict__ ywin, const unsigned short* __restrict__ wqkvH,
    const float* __restrict__ bqkvH, const unsigned short* __restrict__ btabF,
    unsigned short* __restrict__ out)
{
    __shared__ unsigned short As[112 * 196];   // 43,904 B
    __shared__ unsigned short Qs[112 * 46];    // 10,304 B
    __shared__ unsigned short Ks[112 * 46];    // 10,304 B
    __shared__ unsigned short VT[32 * 142];    //  9,088 B   total 73,600 B -> 2 blocks/CU

    const int win = xcd_swz(blockIdx.x, 1520);
    const int t = threadIdx.x;
    const int wid = t >> 6, lane = t & 63;
    const int lg = lane >> 4, l16 = lane & 15;
    const int wr = wid >> 1, wc = wid & 1;
    const size_t rb = (size_t)win * 98;

    const int wdi = win / 190, remw = win % 190, whi = remw / 19, wwi = remw % 19;
    const int mt = (wdi == 7 ? 1 : 0) | (whi == 9 ? 2 : 0) | (wwi == 18 ? 4 : 0);
    const float SCALE = 0.17677669529663687f;

    // zero VT key-cols 112..127 once (read by PV with P==0; must be finite)
    for (int i = t; i < 32 * 16; i += 256) {
        int c = i >> 4, m = 112 + (i & 15);
        VT[c * 142 + m] = 0;
    }
    // stage A rows 0..111 (rows 98..111 zero)
    for (int p = t; p < 112 * 24; p += 256) {
        int row = p / 24, ch = p % 24;
        uint4 w = make_uint4(0u, 0u, 0u, 0u);
        if (row < 98) w = *(const uint4*)(ywin + (rb + row) * 192 + ch * 8);
        *(uint2*)(&As[row * 196 + ch * 8])     = make_uint2(w.x, w.y);
        *(uint2*)(&As[row * 196 + ch * 8 + 4]) = make_uint2(w.z, w.w);
    }

    // B registers for head 0 (rows wc*48 + j*16 + l16 of wqkvH[h])
    bf16x8 breg[3][6];
    {
        const unsigned short* Wh = wqkvH;
        #pragma unroll
        for (int j = 0; j < 3; ++j)
        #pragma unroll
        for (int kb = 0; kb < 6; ++kb)
            breg[j][kb] = load8(Wh + (wc * 48 + j * 16 + l16) * 192 + kb * 32 + 4 * lg);
    }
    __syncthreads();   // A staged (+ VT pad zeroed)

    for (int h = 0; h < 6; ++h) {
        // ---- GEMM: C quadrant [64 x 48] = A @ B^T over K=192 ----
        __builtin_amdgcn_s_setprio(1);
        f32x4 acc[4][3] = {};
        #pragma unroll
        for (int kb = 0; kb < 6; ++kb) {
            bf16x8 af[4];
            #pragma unroll
            for (int i2 = 0; i2 < 4; ++i2)
                if (wr == 0 || i2 < 3)
                    af[i2] = load8(&As[(wr * 64 + i2 * 16 + l16) * 196 + kb * 32 + 4 * lg]);
            #pragma unroll
            for (int i2 = 0; i2 < 4; ++i2)
            #pragma unroll
            for (int j = 0; j < 3; ++j)
                if (wr == 0 || i2 < 3)
                    acc[i2][j] = mfma16(af[i2], breg[j][kb], acc[i2][j]);
        }
        __builtin_amdgcn_s_setprio(0);

        // ---- C + bias -> Qs/Ks/VT ----
        #pragma unroll
        for (int j = 0; j < 3; ++j) {
            int c96 = wc * 48 + j * 16 + l16;
            float bb = bqkvH[h * 96 + c96];
            int which = c96 >> 5, c = c96 & 31;
            #pragma unroll
            for (int i2 = 0; i2 < 4; ++i2) {
                if (wr == 1 && i2 == 3) continue;
                #pragma unroll
                for (int e = 0; e < 4; ++e) {
                    int row = wr * 64 + i2 * 16 + lg * 4 + e;
                    unsigned short val = f2bf(acc[i2][j][e] + bb);
                    if (which == 0)      Qs[row * 46 + c] = val;
                    else if (which == 1) Ks[row * 46 + c] = val;
                    else                 VT[c * 142 + row] = val;
                }
            }
        }
        __syncthreads();   // C visible to all waves

        // ---- attention for head h ----
        const unsigned short* btW = btabF + (size_t)(mt * 6 + h) * 14336;
        #pragma unroll
        for (int fi = 0; fi < 2; ++fi) {
            const int fq = wid + fi * 4;
            if (fq >= 7) break;   // wave-uniform

            const uint4* bp = (const uint4*)(btW + fq * 2048 + l16 * 128 + lg * 32);
            uint4 b0 = bp[0], b1 = bp[1], b2 = bp[2], b3 = bp[3];
            const unsigned bt32[16] = {b0.x, b0.y, b0.z, b0.w, b1.x, b1.y, b1.z, b1.w,
                                       b2.x, b2.y, b2.z, b2.w, b3.x, b3.y, b3.z, b3.w};

            bf16x8 qa = load8(Qs + (fq * 16 + l16) * 46 + 4 * lg);
            f32x4 sc[7];
            #pragma unroll
            for (int fk = 0; fk < 7; ++fk) {
                bf16x8 kb = load8(Ks + (fk * 16 + l16) * 46 + 4 * lg);
                f32x4 z = {};
                sc[fk] = mfma16(kb, qa, z);
            }

            float mx = -1e30f;
            #pragma unroll
            for (int fk = 0; fk < 7; ++fk)
            #pragma unroll
            for (int e = 0; e < 4; ++e) {
                unsigned short bu = (unsigned short)(bt32[fk * 2 + (e >> 1)] >> ((e & 1) * 16));
                float s = fmaf(sc[fk][e], SCALE, bf2f(bu));
                sc[fk][e] = s;
                mx = fmaxf(mx, s);
            }
            mx = fmaxf(mx, __shfl_xor(mx, 16));
            mx = fmaxf(mx, __shfl_xor(mx, 32));
            float sum = 0.f;
            #pragma unroll
            for (int fk = 0; fk < 7; ++fk)
            #pragma unroll
            for (int e = 0; e < 4; ++e) {
                float p = __expf(sc[fk][e] - mx);
                sc[fk][e] = p;
                sum += p;
            }
            sum += __shfl_xor(sum, 16);
            sum += __shfl_xor(sum, 32);
            float rinv = 1.f / sum;

            bf16x8 sa[4];
            #pragma unroll
            for (int ks = 0; ks < 4; ++ks) {
                u32x4 w;
                w[0] = (unsigned)f2bf(sc[2 * ks][0]) | ((unsigned)f2bf(sc[2 * ks][1]) << 16);
                w[1] = (unsigned)f2bf(sc[2 * ks][2]) | ((unsigned)f2bf(sc[2 * ks][3]) << 16);
                if (ks < 3) {
                    w[2] = (unsigned)f2bf(sc[2 * ks + 1][0]) | ((unsigned)f2bf(sc[2 * ks + 1][1]) << 16);
                    w[3] = (unsigned)f2bf(sc[2 * ks + 1][2]) | ((unsigned)f2bf(sc[2 * ks + 1][3]) << 16);
                } else {
                    w[2] = 0u; w[3] = 0u;   // keys 112..127 exact zero
                }
                sa[ks] = __builtin_bit_cast(bf16x8, w);
            }
            float rv[4];
            #pragma unroll
            for (int e = 0; e < 4; ++e) rv[e] = __shfl(rinv, lg * 4 + e);

            #pragma unroll
            for (int fn = 0; fn < 2; ++fn) {
                f32x4 o = {};
                #pragma unroll
                for (int ks = 0; ks < 4; ++ks) {
                    bf16x8 vb = load8(VT + (fn * 16 + l16) * 142 + ks * 32 + 4 * lg);
                    o = mfma16(sa[ks], vb, o);
                }
                #pragma unroll
                for (int e = 0; e < 4; ++e) {
                    int r = fq * 16 + lg * 4 + e;
                    if (r < 98) {
                        out[(rb + r) * 192 + h * 32 + fn * 16 + l16] = f2bf(o[e] * rv[e]);
                    }
                }
            }
        }

        // prefetch next head's B registers (overlaps attn tail; drained at barrier)
        if (h < 5) {
            const unsigned short* Wh = wqkvH + (size_t)(h + 1) * 96 * 192;
            #pragma unroll
            for (int j = 0; j < 3; ++j)
            #pragma unroll
            for (int kb = 0; kb < 6; ++kb)
                breg[j][kb] = load8(Wh + (wc * 48 + j * 16 + l16) * 192 + kb * 32 + 4 * lg);
        }
        __syncthreads();   // attn reads done before next head's C write
    }
}

// ---------- launch ----------
// ws_size = 384 MiB. d_out (fp32 [131072][192]) is ALSO the x1 buffer.
extern "C" void kernel_launch(void* const* d_in, const int* in_sizes, int n_in,
                              void* d_out, int out_size, void* d_ws, size_t ws_size,
                              hipStream_t stream)
{
    const float* x      = (const float*)d_in[0];
    const float* tvec   = (const float*)d_in[2];
    const float* w_qkv  = (const float*)d_in[3];
    const float* b_qkv  = (const float*)d_in[4];
    const float* relb   = (const float*)d_in[5];
    const float* w_proj = (const float*)d_in[6];
    const float* b_proj = (const float*)d_in[7];
    const float* w1     = (const float*)d_in[8];
    const float* b1     = (const float*)d_in[9];
    const float* w2     = (const float*)d_in[10];
    const float* b2     = (const float*)d_in[11];
    const float* wa1    = (const float*)d_in[12];
    const float* wa2    = (const float*)d_in[13];
    const float* ba2    = (const float*)d_in[14];

    char* ws = (char*)d_ws;
    float*          mod    = (float*)ws;                        // 4,608
    float*          bqkvH  = (float*)(ws + 4608);               // 2,304
    unsigned short* wqkvH  = (unsigned short*)(ws + 2101760);   // 221,184
    unsigned short* wprojT = (unsigned short*)(ws + 2322944);   // 73,728
    unsigned short* w1T    = (unsigned short*)(ws + 2396672);   // 294,912
    unsigned short* w2T    = (unsigned short*)(ws + 2691584);   // 294,912
    unsigned short* btabF  = (unsigned short*)(ws + 2986496);   // 1,376,256
    unsigned short* h      = (unsigned short*)(ws + 4834304);   // [131072][768] bf16
    unsigned short* attn_c = (unsigned short*)(ws + 176436224); // [148960][192] bf16
    unsigned short* ywin   = (unsigned short*)(ws + 233636864); // [148960][192] bf16
    unsigned short* y2b    = (unsigned short*)(ws + 290837504); // [131072][192] bf16
    float*          dout   = (float*)d_out;                     // fp32 out == x1 buffer

    mod_k<<<1, 256, 0, stream>>>(tvec, wa1, wa2, ba2, mod);
    prep_k<<<4418, 256, 0, stream>>>(w_qkv, b_qkv, w_proj, w1, w2, relb,
                                     wqkvH, bqkvH, wprojT, w1T, w2T, btabF);
    lnwin_k<<<37240, 256, 0, stream>>>(x, mod, ywin);

    // fused qkv-GEMM + attention (2 blocks/CU)
    qkvattn_k<<<1520, 256, 0, stream>>>(ywin, wqkvH, bqkvH, btabF, attn_c);
    // proj + residual scatter -> fp32 x1 (in d_out)
    gemm_k<2, 2><<<3 * 1164, 256, 0, stream>>>(
        attn_c, wprojT, b_proj, nullptr, dout, x, mod, 148960, 192, 192, 3);

    ln2_k<<<32768, 256, 0, stream>>>(dout, mod, y2b);

    gemm_k<4, 1><<<6 * 1024, 256, 0, stream>>>(
        y2b, w1T, b1, h, nullptr, nullptr, mod, 131072, 768, 192, 6);
    gemm_k<2, 3><<<3 * 1024, 256, 0, stream>>>(
        h, w2T, b2, nullptr, dout, nullptr, mod, 131072, 192, 768, 3);
}